// Round 6
// baseline (2591.988 us; speedup 1.0000x reference)
//
#include <hip/hip_runtime.h>
#include <hip/hip_cooperative_groups.h>

namespace cg = cooperative_groups;

// Fixed shapes
#define B_    64
#define V_    16384
#define E_    524288
#define KCH   6
#define FCH   32
#define FIN1  65536
#define FC1F  512
#define FC2F  512
#define NN1F  1024
#define NN2F  512
#define OUTC  10
#define KT2   64

// workspace layout (bytes), total 16,122,368
#define OFF_XS      0u           // bf16 xs[6][V][B] 12,582,912 ; dead after fc1 -> Cp for back-end
#define OFF_SCOL    12582912u    // u16  scol[E]      1,048,576 ; dead after spmm -> cp_a (fallback)
#define OFF_SVAL    13631488u    // bf16 sval[E]      1,048,576
#define OFF_RSTART  14680064u    // i32  rstart[V+1]
#define OFF_CNT     14746112u    // i32  cnt/cursor[V]
#define OFF_SLICE   15073792u    // bf16 slice[64*8192] 1,048,576 (dead after fc1)
#define OFF_XD      15073792u    // f32  xd[64*512]   (overlays slice)
#define OFF_XN1     15204864u    // f32  xn1[64*1024]
#define OFF_XN2     15467008u    // f32  xn2[64*512]
// fc1 partials (32 x 128 KB = 4 MB) live in out_decode (overwritten later by fc3)

typedef __attribute__((ext_vector_type(4))) float v4f;
typedef __attribute__((ext_vector_type(2))) float v2f;
typedef __attribute__((ext_vector_type(4))) unsigned short u16x4;

__device__ __forceinline__ float b2f(unsigned short h) {
    union { unsigned int u; float f; } v; v.u = ((unsigned int)h) << 16; return v.f;
}
__device__ __forceinline__ unsigned short f2b(float f) {
    union { float f; unsigned int u; } v; v.f = f;
    unsigned int u = v.u;
    u += 0x7fffu + ((u >> 16) & 1u);
    return (unsigned short)(u >> 16);
}

// ---- shared LDS-tiled GEMM block: acc[2][4] += A[64, ka..] @ W[nb..nb+32, kw..]^T
// smem: As[KT2][68] f32 (17408 B) + Ws[KT2][36] f32 (9216 B) = 26624 B
template <int A32>
__device__ __forceinline__ void gemm_block(const void* __restrict__ Av, int lda, int ka,
                                           const float* __restrict__ W, int ldw, int kw,
                                           int klen, int nb, char* smem,
                                           float acc[2][4], int t) {
    float* As = (float*)smem;
    float* Ws = (float*)(smem + KT2 * 68 * 4);
    const unsigned short* Au = (const unsigned short*)Av;
    const float* Af = (const float*)Av;
    int kq = t & 15, r0 = t >> 4;
    int tm = (t & 31) << 1, tn = (t >> 5) << 2;
    for (int kt = 0; kt < klen; kt += KT2) {
        __syncthreads();
        int kk = kq << 2;
        #pragma unroll
        for (int p = 0; p < 4; p++) {
            int row = r0 + p * 16;
            float a0, a1, a2, a3;
            if (A32) {
                v4f v = *(const v4f*)(Af + (size_t)row * lda + ka + kt + kk);
                a0 = v[0]; a1 = v[1]; a2 = v[2]; a3 = v[3];
            } else {
                u16x4 h = *(const u16x4*)(Au + (size_t)row * lda + ka + kt + kk);
                a0 = b2f(h[0]); a1 = b2f(h[1]); a2 = b2f(h[2]); a3 = b2f(h[3]);
            }
            As[(kk + 0) * 68 + row] = a0; As[(kk + 1) * 68 + row] = a1;
            As[(kk + 2) * 68 + row] = a2; As[(kk + 3) * 68 + row] = a3;
        }
        #pragma unroll
        for (int p = 0; p < 2; p++) {
            int row = r0 + p * 16;
            v4f w = *(const v4f*)(W + (size_t)(nb + row) * ldw + kw + kt + kk);
            Ws[(kk + 0) * 36 + row] = w[0]; Ws[(kk + 1) * 36 + row] = w[1];
            Ws[(kk + 2) * 36 + row] = w[2]; Ws[(kk + 3) * 36 + row] = w[3];
        }
        __syncthreads();
        #pragma unroll 8
        for (int k = 0; k < KT2; k++) {
            v2f a = *(const v2f*)&As[k * 68 + tm];
            v4f w = *(const v4f*)&Ws[k * 36 + tn];
            #pragma unroll
            for (int i = 0; i < 2; i++)
                #pragma unroll
                for (int j = 0; j < 4; j++)
                    acc[i][j] += a[i] * w[j];
        }
    }
}

// ===================== cooperative kernels (512 blocks each, 2/CU) =====================

__global__ void __launch_bounds__(256, 2) front_coop_k(
        const float* __restrict__ xin, const int* __restrict__ rows,
        const int* __restrict__ cols, const float* __restrict__ vals,
        unsigned short* __restrict__ xs, unsigned short* __restrict__ scol,
        unsigned short* __restrict__ sval, int* __restrict__ rstart,
        int* __restrict__ cnt) {
    cg::grid_group grid = cg::this_grid();
    int t = threadIdx.x;
    int bx = blockIdx.x;
    __shared__ __align__(16) unsigned short tl[64][66];
    __shared__ int sums[256];

    // Phase A: transpose x_in -> bf16 xs[0] (blocks 0..255); zero cnt (blocks 256..319)
    if (bx < 256) {
        int v0 = bx * 64;
        #pragma unroll
        for (int i = 0; i < 16; i++) {
            int idx = t + i * 256;
            int b = idx >> 6, v = idx & 63;
            tl[v][b] = f2b(xin[(size_t)b * V_ + v0 + v]);
        }
        __syncthreads();
        #pragma unroll
        for (int i = 0; i < 16; i++) {
            int idx = t + i * 256;
            int v = idx >> 6, b = idx & 63;
            xs[(size_t)(v0 + v) * B_ + b] = tl[v][b];
        }
    } else if (bx < 320) {
        cnt[(bx - 256) * 256 + t] = 0;
    }
    grid.sync();

    // Phase B: count (4 edges/thread)
    {
        int idx = bx * 256 + t;
        #pragma unroll
        for (int h = 0; h < 4; h++)
            atomicAdd(&cnt[rows[idx + h * 131072] & (V_ - 1)], 1);
    }
    grid.sync();

    // Phase C: exclusive scan (block 0 only; two-pass, no per-thread arrays)
    if (bx == 0) {
        int s = 0;
        for (int i = 0; i < 64; i++) s += cnt[t * 64 + i];
        sums[t] = s;
        __syncthreads();
        for (int off = 1; off < 256; off <<= 1) {
            int v = (t >= off) ? sums[t - off] : 0;
            __syncthreads();
            sums[t] += v;
            __syncthreads();
        }
        int base = (t == 0) ? 0 : sums[t - 1];
        for (int i = 0; i < 64; i++) {
            int idx = t * 64 + i;
            int c = cnt[idx];
            rstart[idx] = base;
            cnt[idx] = base;          // cursor init
            base += c;
        }
        if (t == 255) rstart[V_] = base;
    }
    grid.sync();

    // Phase D: scatter into CSR
    {
        int idx = bx * 256 + t;
        #pragma unroll
        for (int h = 0; h < 4; h++) {
            int e = idx + h * 131072;
            int r = rows[e] & (V_ - 1);
            int p = atomicAdd(&cnt[r], 1);
            scol[p] = (unsigned short)(cols[e] & (V_ - 1));
            sval[p] = f2b(vals[e]);
        }
    }
    grid.sync();

    // Phase E: Chebyshev recurrence spmm k=1..5 (32 rows/block: 4 waves x 8 rows)
    size_t VB = (size_t)V_ * B_;
    int lane = t & 63;
    int w = t >> 6;
    for (int k = 1; k < KCH; k++) {
        const unsigned short* x = xs + (size_t)(k - 1) * VB;
        const unsigned short* xprev = xs + (size_t)(k >= 2 ? k - 2 : 0) * VB;
        unsigned short* y = xs + (size_t)k * VB;
        for (int rr = 0; rr < 8; rr++) {
            int row = bx * 32 + w * 8 + rr;
            int s = rstart[row], e = rstart[row + 1];
            float a0 = 0.f, a1 = 0.f, a2 = 0.f, a3 = 0.f;
            int i = s;
            for (; i + 4 <= e; i += 4) {
                int c0 = scol[i], c1 = scol[i + 1], c2 = scol[i + 2], c3 = scol[i + 3];
                float v0 = b2f(sval[i]), v1 = b2f(sval[i + 1]);
                float v2 = b2f(sval[i + 2]), v3 = b2f(sval[i + 3]);
                a0 += v0 * b2f(x[(size_t)c0 * B_ + lane]);
                a1 += v1 * b2f(x[(size_t)c1 * B_ + lane]);
                a2 += v2 * b2f(x[(size_t)c2 * B_ + lane]);
                a3 += v3 * b2f(x[(size_t)c3 * B_ + lane]);
            }
            for (; i < e; i++)
                a0 += b2f(sval[i]) * b2f(x[(size_t)scol[i] * B_ + lane]);
            float acc = (a0 + a1) + (a2 + a3);
            size_t o = (size_t)row * B_ + lane;
            float r = (k >= 2) ? (2.f * acc - b2f(xprev[o])) : acc;
            y[o] = f2b(r);
        }
        if (k < KCH - 1) grid.sync();
    }
}

// fc1 = 8 x (cheby-slice phase + gemm phase), accumulator in registers across g
__global__ void __launch_bounds__(256, 2) fc1_coop_k(
        const unsigned short* __restrict__ xs, const float* __restrict__ cw,
        const float* __restrict__ cb, const float* __restrict__ fw,
        const float* __restrict__ fb, unsigned short* __restrict__ slice,
        float* __restrict__ cp, float* __restrict__ outh) {
    cg::grid_group grid = cg::this_grid();
    int t = threadIdx.x;
    int bx = blockIdx.x;
    __shared__ __align__(16) char smem[26624];
    size_t VB = (size_t)V_ * B_;

    float acc[2][4] = {{0.f, 0.f, 0.f, 0.f}, {0.f, 0.f, 0.f, 0.f}};
    int nb = (bx & 15) * 32;
    int y  = bx >> 4;               // 0..31

    for (int g = 0; g < 8; g++) {
        // cheby phase: compute slice(g) [64][8192] bf16 (2 blocks per vp, b-half split)
        {
            float* tile = (float*)smem;            // [6][512]
            float* wf   = tile + KCH * 512;        // [32][6]
            float* bf   = wf + FCH * KCH;          // [32]
            int vpl = bx >> 1;
            int bhalf = bx & 1;
            int vp = g * 256 + vpl;
            for (int i = t; i < KCH * 512; i += 256) {
                int k = i >> 9, rem = i & 511;
                tile[i] = b2f(xs[(size_t)k * VB + (size_t)vp * 512 + rem]);
            }
            if (t < FCH * KCH) wf[t] = cw[t];
            if (t < FCH) bf[t] = cb[t];
            __syncthreads();
            int f = t & 31, b0 = t >> 5;
            float wr[KCH];
            #pragma unroll
            for (int k = 0; k < KCH; k++) wr[k] = wf[f * KCH + k];
            float bb = bf[f];
            #pragma unroll
            for (int bi2 = 0; bi2 < 4; bi2++) {
                int bi = bhalf * 4 + bi2;
                int b = b0 * 8 + bi;
                float m = -1e30f;
                #pragma unroll
                for (int j = 0; j < 8; j++) {
                    float s = bb;
                    #pragma unroll
                    for (int k = 0; k < KCH; k++) s += tile[k * 512 + j * 64 + b] * wr[k];
                    m = fmaxf(m, s);
                }
                slice[(size_t)b * 8192 + vpl * FCH + f] = f2b(fmaxf(m, 0.f));
            }
            __syncthreads();
        }
        grid.sync();
        // gemm phase: acc += slice[:, y*256..+256) @ fc1_w[nb.., g*8192+y*256..)^T
        gemm_block<0>(slice, 8192, y * 256, fw, FIN1, g * 8192 + y * 256, 256, nb, smem, acc, t);
        grid.sync();   // protects slice for next g's cheby write
    }
    // write 32 partial slices into cp (= out_decode scratch, 4 MB)
    {
        int tm = (t & 31) << 1, tn = (t >> 5) << 2;
        float* base = cp + (size_t)y * (64 * FC1F);
        #pragma unroll
        for (int i = 0; i < 2; i++) {
            v4f v;
            #pragma unroll
            for (int j = 0; j < 4; j++) v[j] = acc[i][j];
            *(v4f*)(base + (size_t)(tm + i) * FC1F + nb + tn) = v;
        }
    }
    grid.sync();
    // reduce 32 slices -> out_hidden (relu + bias)
    {
        int idx = bx * 256 + t;
        if (idx < 64 * FC1F) {
            float s = fb[idx & (FC1F - 1)];
            for (int yy = 0; yy < 32; yy++) s += cp[(size_t)yy * (64 * FC1F) + idx];
            outh[idx] = fmaxf(s, 0.f);
        }
    }
}

// fc2 -> xd ; fc3 -> out_decode ; nn1 -> xn1 ; nn2 -> xn2 ; sum2
__global__ void __launch_bounds__(256, 2) back_coop_k(
        const float* __restrict__ outh, const float* __restrict__ fc2w,
        const float* __restrict__ fc2b, float* __restrict__ xd,
        const float* __restrict__ fc3w, const float* __restrict__ fc3b,
        float* __restrict__ outd, const float* __restrict__ xin,
        const float* __restrict__ nn1w, const float* __restrict__ nn1b,
        float* __restrict__ xn1, const float* __restrict__ nn2w,
        const float* __restrict__ nn2b, float* __restrict__ xn2,
        const float* __restrict__ s2w, const float* __restrict__ s2b,
        float* __restrict__ logp, float* __restrict__ cpb) {
    cg::grid_group grid = cg::this_grid();
    int t = threadIdx.x;
    int bx = blockIdx.x;
    __shared__ __align__(16) char smem[26624];
    int tm = (t & 31) << 1, tn = (t >> 5) << 2;

    // P0: fc2 partials (blocks 0..127: n = bx&15, y = bx>>4 in [0,8), klen=64)
    if (bx < 128) {
        int nb = (bx & 15) * 32, y = bx >> 4;
        float acc[2][4] = {{0.f, 0.f, 0.f, 0.f}, {0.f, 0.f, 0.f, 0.f}};
        gemm_block<1>(outh, FC1F, y * 64, fc2w, FC1F, y * 64, 64, nb, smem, acc, t);
        float* base = cpb + (size_t)y * (64 * FC2F);
        #pragma unroll
        for (int i = 0; i < 2; i++) {
            v4f v;
            #pragma unroll
            for (int j = 0; j < 4; j++) v[j] = acc[i][j];
            *(v4f*)(base + (size_t)(tm + i) * FC2F + nb + tn) = v;
        }
    }
    grid.sync();
    // P1: reduce fc2 -> xd (relu)
    {
        int idx = bx * 256 + t;
        if (idx < 64 * FC2F) {
            float s = fc2b[idx & (FC2F - 1)];
            for (int yy = 0; yy < 8; yy++) s += cpb[(size_t)yy * (64 * FC2F) + idx];
            xd[idx] = fmaxf(s, 0.f);
        }
    }
    grid.sync();
    // P2: fc3 direct (all 512 blocks, nb = bx*32, K=512) -> out_decode
    {
        int nb = bx * 32;
        float acc[2][4] = {{0.f, 0.f, 0.f, 0.f}, {0.f, 0.f, 0.f, 0.f}};
        gemm_block<1>(xd, FC2F, 0, fc3w, FC2F, 0, FC2F, nb, smem, acc, t);
        #pragma unroll
        for (int i = 0; i < 2; i++) {
            v4f v;
            #pragma unroll
            for (int j = 0; j < 4; j++) v[j] = acc[i][j] + fc3b[nb + tn + j];
            *(v4f*)(outd + (size_t)(tm + i) * V_ + nb + tn) = v;
        }
    }
    // P3: nn1 partials (all 512: n = bx&31, y = bx>>5 in [0,16), klen=1024)
    {
        int nb = (bx & 31) * 32, y = bx >> 5;
        float acc[2][4] = {{0.f, 0.f, 0.f, 0.f}, {0.f, 0.f, 0.f, 0.f}};
        gemm_block<1>(xin, V_, y * 1024, nn1w, V_, y * 1024, 1024, nb, smem, acc, t);
        float* base = cpb + (size_t)y * (64 * NN1F);
        #pragma unroll
        for (int i = 0; i < 2; i++) {
            v4f v;
            #pragma unroll
            for (int j = 0; j < 4; j++) v[j] = acc[i][j];
            *(v4f*)(base + (size_t)(tm + i) * NN1F + nb + tn) = v;
        }
    }
    grid.sync();
    // P4: reduce nn1 -> xn1 (relu)
    {
        int idx = bx * 256 + t;
        if (idx < 64 * NN1F) {
            float s = nn1b[idx & (NN1F - 1)];
            for (int yy = 0; yy < 16; yy++) s += cpb[(size_t)yy * (64 * NN1F) + idx];
            xn1[idx] = fmaxf(s, 0.f);
        }
    }
    grid.sync();
    // P5: nn2 partials (blocks 0..255: n = bx&15, y = bx>>4 in [0,16), klen=64)
    if (bx < 256) {
        int nb = (bx & 15) * 32, y = bx >> 4;
        float acc[2][4] = {{0.f, 0.f, 0.f, 0.f}, {0.f, 0.f, 0.f, 0.f}};
        gemm_block<1>(xn1, NN1F, y * 64, nn2w, NN1F, y * 64, 64, nb, smem, acc, t);
        float* base = cpb + (size_t)y * (64 * NN2F);
        #pragma unroll
        for (int i = 0; i < 2; i++) {
            v4f v;
            #pragma unroll
            for (int j = 0; j < 4; j++) v[j] = acc[i][j];
            *(v4f*)(base + (size_t)(tm + i) * NN2F + nb + tn) = v;
        }
    }
    grid.sync();
    // P6: reduce nn2 -> xn2 (relu)
    {
        int idx = bx * 256 + t;
        if (idx < 64 * NN2F) {
            float s = nn2b[idx & (NN2F - 1)];
            for (int yy = 0; yy < 16; yy++) s += cpb[(size_t)yy * (64 * NN2F) + idx];
            xn2[idx] = fmaxf(s, 0.f);
        }
    }
    grid.sync();
    // P7: sum2 + log_softmax (blocks 0..63, wave 0)
    if (bx < 64 && t < 64) {
        int b = bx, lane = t;
        float xc[16];
        #pragma unroll
        for (int j = 0; j < 8; j++) xc[j] = outh[b * FC1F + j * 64 + lane];
        #pragma unroll
        for (int j = 0; j < 8; j++) xc[8 + j] = xn2[b * NN2F + j * 64 + lane];
        float logits[OUTC];
        #pragma unroll
        for (int o = 0; o < OUTC; o++) {
            float s = 0.f;
            #pragma unroll
            for (int j = 0; j < 16; j++) s += xc[j] * s2w[o * 1024 + j * 64 + lane];
            #pragma unroll
            for (int off = 32; off; off >>= 1) s += __shfl_xor(s, off);
            logits[o] = s + s2b[o];
        }
        float mx = logits[0];
        #pragma unroll
        for (int o = 1; o < OUTC; o++) mx = fmaxf(mx, logits[o]);
        float lse = 0.f;
        #pragma unroll
        for (int o = 0; o < OUTC; o++) lse += expf(logits[o] - mx);
        float lg = logf(lse) + mx;
        if (lane < OUTC) logp[b * OUTC + lane] = logits[lane] - lg;
    }
}

// ===================== fallback kernels (proven round-4 path) =====================

__global__ void prep_k(const float* __restrict__ xin, unsigned short* __restrict__ x0) {
    __shared__ unsigned short tl[64][65];
    int t = threadIdx.x;
    int v0 = blockIdx.x * 64;
    #pragma unroll
    for (int i = 0; i < 16; i++) {
        int idx = t + i * 256;
        int b = idx >> 6, v = idx & 63;
        tl[v][b] = f2b(xin[(size_t)b * V_ + v0 + v]);
    }
    __syncthreads();
    #pragma unroll
    for (int i = 0; i < 16; i++) {
        int idx = t + i * 256;
        int v = idx >> 6, b = idx & 63;
        x0[(size_t)(v0 + v) * B_ + b] = tl[v][b];
    }
}

__global__ void count_k(const int* __restrict__ rows, int* __restrict__ cnt) {
    int e = blockIdx.x * 256 + threadIdx.x;
    if (e < E_) atomicAdd(&cnt[rows[e] & (V_ - 1)], 1);
}

__global__ void scan_k(int* __restrict__ cnt_cursor, int* __restrict__ row_start) {
    __shared__ int sums[256];
    int t = threadIdx.x;
    int s = 0;
    for (int i = 0; i < 64; i++) s += cnt_cursor[t * 64 + i];
    sums[t] = s;
    __syncthreads();
    for (int off = 1; off < 256; off <<= 1) {
        int v = (t >= off) ? sums[t - off] : 0;
        __syncthreads();
        sums[t] += v;
        __syncthreads();
    }
    int base = (t == 0) ? 0 : sums[t - 1];
    for (int i = 0; i < 64; i++) {
        int idx = t * 64 + i;
        int c = cnt_cursor[idx];
        row_start[idx] = base;
        cnt_cursor[idx] = base;
        base += c;
    }
    if (t == 255) row_start[V_] = base;
}

__global__ void scatter_k(const int* __restrict__ rows, const int* __restrict__ cols,
                          const float* __restrict__ vals,
                          int* __restrict__ cursor, unsigned short* __restrict__ scol,
                          unsigned short* __restrict__ sval) {
    int e = blockIdx.x * 256 + threadIdx.x;
    if (e < E_) {
        int r = rows[e] & (V_ - 1);
        int p = atomicAdd(&cursor[r], 1);
        scol[p] = (unsigned short)(cols[e] & (V_ - 1));
        sval[p] = f2b(vals[e]);
    }
}

__global__ void spmm_k(const int* __restrict__ row_start, const unsigned short* __restrict__ scol,
                       const unsigned short* __restrict__ sval,
                       const unsigned short* __restrict__ x,
                       const unsigned short* __restrict__ xprev, unsigned short* __restrict__ y,
                       int mode) {
    int row  = blockIdx.x * 4 + (threadIdx.x >> 6);
    int lane = threadIdx.x & 63;
    int s = row_start[row], e = row_start[row + 1];
    float a0 = 0.f, a1 = 0.f, a2 = 0.f, a3 = 0.f;
    int i = s;
    for (; i + 4 <= e; i += 4) {
        int c0 = scol[i], c1 = scol[i + 1], c2 = scol[i + 2], c3 = scol[i + 3];
        float v0 = b2f(sval[i]), v1 = b2f(sval[i + 1]);
        float v2 = b2f(sval[i + 2]), v3 = b2f(sval[i + 3]);
        a0 += v0 * b2f(x[(size_t)c0 * B_ + lane]);
        a1 += v1 * b2f(x[(size_t)c1 * B_ + lane]);
        a2 += v2 * b2f(x[(size_t)c2 * B_ + lane]);
        a3 += v3 * b2f(x[(size_t)c3 * B_ + lane]);
    }
    for (; i < e; i++)
        a0 += b2f(sval[i]) * b2f(x[(size_t)scol[i] * B_ + lane]);
    float acc = (a0 + a1) + (a2 + a3);
    size_t o = (size_t)row * B_ + lane;
    float r = mode ? (2.f * acc - b2f(xprev[o])) : acc;
    y[o] = f2b(r);
}

__global__ void cheby_slice_k(const unsigned short* __restrict__ xs, const float* __restrict__ w,
                              const float* __restrict__ bias, unsigned short* __restrict__ slice,
                              int g) {
    __shared__ float tile[KCH * 512];
    __shared__ float wf[FCH * KCH];
    __shared__ float bf[FCH];
    int t = threadIdx.x;
    int vpl = blockIdx.x;
    int vp = g * 256 + vpl;
    for (int i = t; i < KCH * 512; i += 256) {
        int k = i >> 9, rem = i & 511;
        tile[i] = b2f(xs[(size_t)k * V_ * B_ + (size_t)vp * 512 + rem]);
    }
    if (t < FCH * KCH) wf[t] = w[t];
    if (t < FCH) bf[t] = bias[t];
    __syncthreads();
    int f = t & 31, b0 = t >> 5;
    float wr[KCH];
    #pragma unroll
    for (int k = 0; k < KCH; k++) wr[k] = wf[f * KCH + k];
    float bb = bf[f];
    #pragma unroll
    for (int bi = 0; bi < 8; bi++) {
        int b = b0 * 8 + bi;
        float m = -1e30f;
        #pragma unroll
        for (int j = 0; j < 8; j++) {
            float s = bb;
            #pragma unroll
            for (int k = 0; k < KCH; k++) s += tile[k * 512 + j * 64 + b] * wr[k];
            m = fmaxf(m, s);
        }
        slice[(size_t)b * 8192 + vpl * FCH + f] = f2b(fmaxf(m, 0.f));
    }
}

__global__ void gemm3_k(const void* __restrict__ Av, int a32, int lda, int ka0,
                        const float* __restrict__ W, int ldw, int kw0,
                        int klen, int N, const float* __restrict__ bias,
                        int relu, int direct, int accum,
                        float* __restrict__ Cp, float* __restrict__ Co) {
    __shared__ __align__(16) char smem[26624];
    int t = threadIdx.x;
    int nb = blockIdx.x * 32;
    int ka = ka0 + blockIdx.y * klen;
    int kw = kw0 + blockIdx.y * klen;
    int tm = (t & 31) << 1, tn = (t >> 5) << 2;
    float acc[2][4] = {{0.f, 0.f, 0.f, 0.f}, {0.f, 0.f, 0.f, 0.f}};
    if (a32) gemm_block<1>(Av, lda, ka, W, ldw, kw, klen, nb, smem, acc, t);
    else     gemm_block<0>(Av, lda, ka, W, ldw, kw, klen, nb, smem, acc, t);
    if (direct) {
        #pragma unroll
        for (int i = 0; i < 2; i++) {
            int m = tm + i;
            v4f v;
            #pragma unroll
            for (int j = 0; j < 4; j++) {
                float x = acc[i][j] + bias[nb + tn + j];
                v[j] = relu ? fmaxf(x, 0.f) : x;
            }
            *(v4f*)(Co + (size_t)m * N + nb + tn) = v;
        }
    } else {
        float* base = Cp + (size_t)blockIdx.y * 64 * N;
        #pragma unroll
        for (int i = 0; i < 2; i++) {
            int m = tm + i;
            float* p = base + (size_t)m * N + nb + tn;
            v4f v;
            if (accum) {
                v4f old = *(const v4f*)p;
                #pragma unroll
                for (int j = 0; j < 4; j++) v[j] = old[j] + acc[i][j];
            } else {
                #pragma unroll
                for (int j = 0; j < 4; j++) v[j] = acc[i][j];
            }
            *(v4f*)p = v;
        }
    }
}

__global__ void finish2_k(const float* __restrict__ Cp, int Y, int len,
                          const float* __restrict__ bias, int nmask, int relu,
                          float* __restrict__ o) {
    int i = blockIdx.x * 256 + threadIdx.x;
    float s = bias[i & nmask];
    for (int y = 0; y < Y; y++) s += Cp[(size_t)y * len + i];
    if (relu) s = fmaxf(s, 0.f);
    o[i] = s;
}

__global__ void sum2_k(const float* __restrict__ xh, const float* __restrict__ xn,
                       const float* __restrict__ w, const float* __restrict__ bias,
                       float* __restrict__ out) {
    int b = blockIdx.x;
    int lane = threadIdx.x;
    float xc[16];
    #pragma unroll
    for (int j = 0; j < 8; j++) xc[j] = xh[b * FC1F + j * 64 + lane];
    #pragma unroll
    for (int j = 0; j < 8; j++) xc[8 + j] = xn[b * NN2F + j * 64 + lane];
    float logits[OUTC];
    #pragma unroll
    for (int o = 0; o < OUTC; o++) {
        float s = 0.f;
        #pragma unroll
        for (int j = 0; j < 16; j++) s += xc[j] * w[o * 1024 + j * 64 + lane];
        #pragma unroll
        for (int off = 32; off; off >>= 1) s += __shfl_xor(s, off);
        logits[o] = s + bias[o];
    }
    float mx = logits[0];
    #pragma unroll
    for (int o = 1; o < OUTC; o++) mx = fmaxf(mx, logits[o]);
    float lse = 0.f;
    #pragma unroll
    for (int o = 0; o < OUTC; o++) lse += expf(logits[o] - mx);
    float lg = logf(lse) + mx;
    if (lane < OUTC) out[b * OUTC + lane] = logits[lane] - lg;
}

extern "C" void kernel_launch(void* const* d_in, const int* in_sizes, int n_in,
                              void* d_out, int out_size, void* d_ws, size_t ws_size,
                              hipStream_t stream) {
    const float* x_in   = (const float*)d_in[0];
    const float* L_vals = (const float*)d_in[1];
    const float* cl1_w  = (const float*)d_in[2];
    const float* cl1_b  = (const float*)d_in[3];
    const float* fc1_w  = (const float*)d_in[4];
    const float* fc1_b  = (const float*)d_in[5];
    const float* fc2_w  = (const float*)d_in[6];
    const float* fc2_b  = (const float*)d_in[7];
    const float* fc3_w  = (const float*)d_in[8];
    const float* fc3_b  = (const float*)d_in[9];
    const float* nn1_w  = (const float*)d_in[10];
    const float* nn1_b  = (const float*)d_in[11];
    const float* nn2_w  = (const float*)d_in[12];
    const float* nn2_b  = (const float*)d_in[13];
    const float* sum2_w = (const float*)d_in[14];
    const float* sum2_b = (const float*)d_in[15];
    const int* L_rows = (const int*)d_in[16];
    const int* L_cols = (const int*)d_in[17];
    float* out = (float*)d_out;
    char* ws = (char*)d_ws;

    unsigned short* xs     = (unsigned short*)(ws + OFF_XS);
    unsigned short* scol   = (unsigned short*)(ws + OFF_SCOL);
    unsigned short* sval   = (unsigned short*)(ws + OFF_SVAL);
    int*            rstart = (int*)(ws + OFF_RSTART);
    int*            cnt    = (int*)(ws + OFF_CNT);
    unsigned short* slice  = (unsigned short*)(ws + OFF_SLICE);
    float*          xd     = (float*)(ws + OFF_XD);
    float*          xn1    = (float*)(ws + OFF_XN1);
    float*          xn2    = (float*)(ws + OFF_XN2);
    float*          cp_a   = (float*)(ws + OFF_SCOL);   // fallback fc1/fc2 partials (2 MB)
    float*          cpb    = (float*)(ws + OFF_XS);     // back-end partials (xs dead, <=4 MB)

    float* out_decode = out;                            // f32 [64,16384]; also fc1 partial scratch
    float* out_hidden = out + (size_t)B_ * V_;          // f32 [64,512]
    float* out_logp   = out_hidden + B_ * FC1F;         // f32 [64,10]
    float* cp_fc1     = out_decode;

    size_t VB = (size_t)V_ * B_;
    bool front_done = false, fc1_done = false, back_done = false;

    // ---- try cooperative path ----
    {
        void* args[] = {(void*)&x_in, (void*)&L_rows, (void*)&L_cols, (void*)&L_vals,
                        (void*)&xs, (void*)&scol, (void*)&sval, (void*)&rstart, (void*)&cnt};
        if (hipLaunchCooperativeKernel((const void*)front_coop_k, dim3(512), dim3(256),
                                       args, 0, stream) == hipSuccess)
            front_done = true;
    }
    if (front_done) {
        void* args[] = {(void*)&xs, (void*)&cl1_w, (void*)&cl1_b, (void*)&fc1_w, (void*)&fc1_b,
                        (void*)&slice, (void*)&cp_fc1, (void*)&out_hidden};
        if (hipLaunchCooperativeKernel((const void*)fc1_coop_k, dim3(512), dim3(256),
                                       args, 0, stream) == hipSuccess)
            fc1_done = true;
    }
    if (fc1_done) {
        void* args[] = {(void*)&out_hidden, (void*)&fc2_w, (void*)&fc2_b, (void*)&xd,
                        (void*)&fc3_w, (void*)&fc3_b, (void*)&out_decode, (void*)&x_in,
                        (void*)&nn1_w, (void*)&nn1_b, (void*)&xn1,
                        (void*)&nn2_w, (void*)&nn2_b, (void*)&xn2,
                        (void*)&sum2_w, (void*)&sum2_b, (void*)&out_logp, (void*)&cpb};
        if (hipLaunchCooperativeKernel((const void*)back_coop_k, dim3(512), dim3(256),
                                       args, 0, stream) == hipSuccess)
            back_done = true;
    }

    // ---- fallback stages (proven round-4 path) ----
    if (!front_done) {
        prep_k<<<V_ / 64, 256, 0, stream>>>(x_in, xs);
        hipMemsetAsync(cnt, 0, V_ * sizeof(int), stream);
        count_k<<<E_ / 256, 256, 0, stream>>>(L_rows, cnt);
        scan_k<<<1, 256, 0, stream>>>(cnt, rstart);
        scatter_k<<<E_ / 256, 256, 0, stream>>>(L_rows, L_cols, L_vals, cnt, scol, sval);
        spmm_k<<<V_ / 4, 256, 0, stream>>>(rstart, scol, sval, xs, nullptr, xs + VB, 0);
        for (int k = 2; k < KCH; k++)
            spmm_k<<<V_ / 4, 256, 0, stream>>>(rstart, scol, sval,
                                               xs + (k - 1) * VB, xs + (k - 2) * VB, xs + k * VB, 1);
    }
    if (!fc1_done) {
        for (int g = 0; g < 8; g++) {
            cheby_slice_k<<<256, 256, 0, stream>>>(xs, cl1_w, cl1_b, slice, g);
            gemm3_k<<<dim3(FC1F / 32, 16), 256, 0, stream>>>(slice, 0, 8192, 0,
                                                             fc1_w, FIN1, g * 8192,
                                                             512, FC1F, nullptr, 0, 0, g ? 1 : 0,
                                                             cp_a, nullptr);
        }
        finish2_k<<<B_ * FC1F / 256, 256, 0, stream>>>(cp_a, 16, B_ * FC1F, fc1_b, FC1F - 1, 1,
                                                       out_hidden);
    }
    if (!back_done) {
        gemm3_k<<<dim3(FC2F / 32, 8), 256, 0, stream>>>(out_hidden, 1, FC1F, 0,
                                                        fc2_w, FC1F, 0,
                                                        64, FC2F, nullptr, 0, 0, 0, cp_a, nullptr);
        finish2_k<<<B_ * FC2F / 256, 256, 0, stream>>>(cp_a, 8, B_ * FC2F, fc2_b, FC2F - 1, 1, xd);
        gemm3_k<<<dim3(V_ / 32, 1), 256, 0, stream>>>(xd, 1, FC2F, 0,
                                                      fc3_w, FC2F, 0,
                                                      FC2F, V_, fc3_b, 0, 1, 0, nullptr, out_decode);
        gemm3_k<<<dim3(NN1F / 32, 32), 256, 0, stream>>>(x_in, 1, V_, 0,
                                                         nn1_w, V_, 0,
                                                         512, NN1F, nullptr, 0, 0, 0, cpb, nullptr);
        finish2_k<<<B_ * NN1F / 256, 256, 0, stream>>>(cpb, 32, B_ * NN1F, nn1_b, NN1F - 1, 1, xn1);
        gemm3_k<<<dim3(NN2F / 32, 16), 256, 0, stream>>>(xn1, 1, NN1F, 0,
                                                         nn2_w, NN1F, 0,
                                                         64, NN2F, nullptr, 0, 0, 0, cpb, nullptr);
        finish2_k<<<B_ * NN2F / 256, 256, 0, stream>>>(cpb, 16, B_ * NN2F, nn2_b, NN2F - 1, 1, xn2);
        sum2_k<<<B_, 64, 0, stream>>>(out_hidden, xn2, sum2_w, sum2_b, out_logp);
    }
}

// Round 7
// 719.142 us; speedup vs baseline: 3.6043x; 3.6043x over previous
//
#include <hip/hip_runtime.h>

// Fixed shapes
#define B_    64
#define V_    16384
#define E_    524288
#define KCH   6
#define FCH   32
#define FIN1  65536
#define FC1F  512
#define FC2F  512
#define NN1F  1024
#define NN2F  512
#define OUTC  10
#define KT2   64

// workspace layout (bytes), total 16,122,368
#define OFF_XS      0u           // bf16 xs[6][V][B] 12,582,912 ; dead after fc1 -> Cp_nn1/Cp_nn2
#define OFF_SCOL    12582912u    // u16  scol[E] 1 MB ; +sval = 2 MB ; dead after spmm -> slice_q (2 MB)
#define OFF_SVAL    13631488u    // bf16 sval[E] 1 MB
#define OFF_RSTART  14680064u    // i32  rstart[V+1]
#define OFF_CNT     14746112u    // i32  cnt/cursor[V]
#define OFF_XD      15073792u    // f32  xd[64*512]
#define OFF_XN1     15204864u    // f32  xn1[64*1024]
#define OFF_CPN2    4194304u     // f32  Cp_nn2[4][64][512] (in dead xs, after Cp_nn1's 4 MB)
// fc1 Cp[32][64][512] = 4 MB lives in out_decode (overwritten later by fc3)
// nn1 Cp[16][64][1024] = 4 MB lives at ws+0 (dead xs)

typedef __attribute__((ext_vector_type(4))) float v4f;
typedef __attribute__((ext_vector_type(2))) float v2f;
typedef __attribute__((ext_vector_type(4))) unsigned short u16x4;

__device__ __forceinline__ float b2f(unsigned short h) {
    union { unsigned int u; float f; } v; v.u = ((unsigned int)h) << 16; return v.f;
}
__device__ __forceinline__ unsigned short f2b(float f) {
    union { float f; unsigned int u; } v; v.f = f;
    unsigned int u = v.u;
    u += 0x7fffu + ((u >> 16) & 1u);
    return (unsigned short)(u >> 16);
}

// ---- LDS-tiled GEMM core: acc[2][4] += A[64, ka..] @ W[nb..nb+32, kw..]^T
// As pad 66 (write conflicts 8-way -> 4-way, keeps v2f 8B alignment); Ws pad 36.
// smem: As 64*66*4 = 16896 B + Ws 64*36*4 = 9216 B = 26112 B
template <int A32>
__device__ __forceinline__ void gemm_block(const void* __restrict__ Av, int lda, int ka,
                                           const float* __restrict__ W, int ldw, int kw,
                                           int klen, int nb, char* smem,
                                           float acc[2][4], int t) {
    float* As = (float*)smem;
    float* Ws = (float*)(smem + KT2 * 66 * 4);
    const unsigned short* Au = (const unsigned short*)Av;
    const float* Af = (const float*)Av;
    int kq = t & 15, r0 = t >> 4;
    int tm = (t & 31) << 1, tn = (t >> 5) << 2;
    for (int kt = 0; kt < klen; kt += KT2) {
        __syncthreads();
        int kk = kq << 2;
        #pragma unroll
        for (int p = 0; p < 4; p++) {
            int row = r0 + p * 16;
            float a0, a1, a2, a3;
            if (A32) {
                v4f v = *(const v4f*)(Af + (size_t)row * lda + ka + kt + kk);
                a0 = v[0]; a1 = v[1]; a2 = v[2]; a3 = v[3];
            } else {
                u16x4 h = *(const u16x4*)(Au + (size_t)row * lda + ka + kt + kk);
                a0 = b2f(h[0]); a1 = b2f(h[1]); a2 = b2f(h[2]); a3 = b2f(h[3]);
            }
            As[(kk + 0) * 66 + row] = a0; As[(kk + 1) * 66 + row] = a1;
            As[(kk + 2) * 66 + row] = a2; As[(kk + 3) * 66 + row] = a3;
        }
        #pragma unroll
        for (int p = 0; p < 2; p++) {
            int row = r0 + p * 16;
            v4f w = *(const v4f*)(W + (size_t)(nb + row) * ldw + kw + kt + kk);
            Ws[(kk + 0) * 36 + row] = w[0]; Ws[(kk + 1) * 36 + row] = w[1];
            Ws[(kk + 2) * 36 + row] = w[2]; Ws[(kk + 3) * 36 + row] = w[3];
        }
        __syncthreads();
        #pragma unroll 8
        for (int k = 0; k < KT2; k++) {
            v2f a = *(const v2f*)&As[k * 66 + tm];
            v4f w = *(const v4f*)&Ws[k * 36 + tn];
            #pragma unroll
            for (int i = 0; i < 2; i++)
                #pragma unroll
                for (int j = 0; j < 4; j++)
                    acc[i][j] += a[i] * w[j];
        }
    }
}

// fused: blocks 0..255 transpose x_in -> bf16 xs[0]; blocks 256..767 count rows (cnt pre-zeroed)
__global__ void prepcount_k(const float* __restrict__ xin, unsigned short* __restrict__ x0,
                            const int* __restrict__ rows, int* __restrict__ cnt) {
    int t = threadIdx.x;
    int bx = blockIdx.x;
    if (bx < 256) {
        __shared__ unsigned short tl[64][65];
        int v0 = bx * 64;
        #pragma unroll
        for (int i = 0; i < 16; i++) {
            int idx = t + i * 256;
            int b = idx >> 6, v = idx & 63;
            tl[v][b] = f2b(xin[(size_t)b * V_ + v0 + v]);
        }
        __syncthreads();
        #pragma unroll
        for (int i = 0; i < 16; i++) {
            int idx = t + i * 256;
            int v = idx >> 6, b = idx & 63;
            x0[(size_t)(v0 + v) * B_ + b] = tl[v][b];
        }
    } else {
        int idx = (bx - 256) * 256 + t;
        #pragma unroll
        for (int h = 0; h < 4; h++)
            atomicAdd(&cnt[rows[idx + h * 131072] & (V_ - 1)], 1);
    }
}

__global__ void scan_k(int* __restrict__ cnt_cursor, int* __restrict__ row_start) {
    __shared__ int sums[256];
    int t = threadIdx.x;
    int s = 0;
    for (int i = 0; i < 64; i++) s += cnt_cursor[t * 64 + i];
    sums[t] = s;
    __syncthreads();
    for (int off = 1; off < 256; off <<= 1) {
        int v = (t >= off) ? sums[t - off] : 0;
        __syncthreads();
        sums[t] += v;
        __syncthreads();
    }
    int base = (t == 0) ? 0 : sums[t - 1];
    for (int i = 0; i < 64; i++) {
        int idx = t * 64 + i;
        int c = cnt_cursor[idx];
        row_start[idx] = base;
        cnt_cursor[idx] = base;
        base += c;
    }
    if (t == 255) row_start[V_] = base;
}

__global__ void scatter_k(const int* __restrict__ rows, const int* __restrict__ cols,
                          const float* __restrict__ vals,
                          int* __restrict__ cursor, unsigned short* __restrict__ scol,
                          unsigned short* __restrict__ sval) {
    int idx = blockIdx.x * 256 + threadIdx.x;
    #pragma unroll
    for (int h = 0; h < 4; h++) {
        int e = idx + h * 131072;
        int r = rows[e] & (V_ - 1);
        int p = atomicAdd(&cursor[r], 1);
        scol[p] = (unsigned short)(cols[e] & (V_ - 1));
        sval[p] = f2b(vals[e]);
    }
}

// one wave per row; 4-way unrolled gather for ILP
__global__ void spmm_k(const int* __restrict__ row_start, const unsigned short* __restrict__ scol,
                       const unsigned short* __restrict__ sval,
                       const unsigned short* __restrict__ x,
                       const unsigned short* __restrict__ xprev, unsigned short* __restrict__ y,
                       int mode) {
    int row  = blockIdx.x * 4 + (threadIdx.x >> 6);
    int lane = threadIdx.x & 63;
    int s = row_start[row], e = row_start[row + 1];
    float a0 = 0.f, a1 = 0.f, a2 = 0.f, a3 = 0.f;
    int i = s;
    for (; i + 4 <= e; i += 4) {
        int c0 = scol[i], c1 = scol[i + 1], c2 = scol[i + 2], c3 = scol[i + 3];
        float v0 = b2f(sval[i]), v1 = b2f(sval[i + 1]);
        float v2 = b2f(sval[i + 2]), v3 = b2f(sval[i + 3]);
        a0 += v0 * b2f(x[(size_t)c0 * B_ + lane]);
        a1 += v1 * b2f(x[(size_t)c1 * B_ + lane]);
        a2 += v2 * b2f(x[(size_t)c2 * B_ + lane]);
        a3 += v3 * b2f(x[(size_t)c3 * B_ + lane]);
    }
    for (; i < e; i++)
        a0 += b2f(sval[i]) * b2f(x[(size_t)scol[i] * B_ + lane]);
    float acc = (a0 + a1) + (a2 + a3);
    size_t o = (size_t)row * B_ + lane;
    float r = mode ? (2.f * acc - b2f(xprev[o])) : acc;
    y[o] = f2b(r);
}

// cheby conv + relu + maxpool for one QUARTER of the pooled-vertex range.
// 512 blocks, one vp per block; writes slice[b][vpl*32+f], row-stride 16384 (2 MB bf16).
__global__ void cheby_q_k(const unsigned short* __restrict__ xs, const float* __restrict__ w,
                          const float* __restrict__ bias, unsigned short* __restrict__ slice,
                          int q) {
    __shared__ float tile[KCH * 512];
    __shared__ float wf[FCH * KCH];
    __shared__ float bf[FCH];
    int t = threadIdx.x;
    int vpl = blockIdx.x;
    int vp = q * 512 + vpl;
    for (int i = t; i < KCH * 512; i += 256) {
        int k = i >> 9, rem = i & 511;
        tile[i] = b2f(xs[(size_t)k * V_ * B_ + (size_t)vp * 512 + rem]);
    }
    if (t < FCH * KCH) wf[t] = w[t];
    if (t < FCH) bf[t] = bias[t];
    __syncthreads();
    int f = t & 31, b0 = t >> 5;
    float wr[KCH];
    #pragma unroll
    for (int k = 0; k < KCH; k++) wr[k] = wf[f * KCH + k];
    float bb = bf[f];
    #pragma unroll
    for (int bi = 0; bi < 8; bi++) {
        int b = b0 * 8 + bi;
        float m = -1e30f;
        #pragma unroll
        for (int j = 0; j < 8; j++) {
            float s = bb;
            #pragma unroll
            for (int k = 0; k < KCH; k++) s += tile[k * 512 + j * 64 + b] * wr[k];
            m = fmaxf(m, s);
        }
        slice[(size_t)b * 16384 + vpl * FCH + f] = f2b(fmaxf(m, 0.f));
    }
}

// generic GEMM: C[64,N] = A[64,K] @ W[N,K]^T ; 64m x 32n block tile.
// grid.x = N/32, grid.y = K-split. direct=1: Co = acc+bias (relu?).
// direct=0: Cp[y][64][N] = acc (accum=0) or += acc (accum=1).
__global__ void gemm4_k(const void* __restrict__ Av, int a32, int lda, int ka0,
                        const float* __restrict__ W, int ldw, int kw0,
                        int klen, int N, const float* __restrict__ bias,
                        int relu, int direct, int accum,
                        float* __restrict__ Cp, float* __restrict__ Co) {
    __shared__ __align__(16) char smem[26112];
    int t = threadIdx.x;
    int nb = blockIdx.x * 32;
    int ka = ka0 + blockIdx.y * klen;
    int kw = kw0 + blockIdx.y * klen;
    int tm = (t & 31) << 1, tn = (t >> 5) << 2;
    float acc[2][4] = {{0.f, 0.f, 0.f, 0.f}, {0.f, 0.f, 0.f, 0.f}};
    if (a32) gemm_block<1>(Av, lda, ka, W, ldw, kw, klen, nb, smem, acc, t);
    else     gemm_block<0>(Av, lda, ka, W, ldw, kw, klen, nb, smem, acc, t);
    if (direct) {
        #pragma unroll
        for (int i = 0; i < 2; i++) {
            int m = tm + i;
            v4f v;
            #pragma unroll
            for (int j = 0; j < 4; j++) {
                float x = acc[i][j] + bias[nb + tn + j];
                v[j] = relu ? fmaxf(x, 0.f) : x;
            }
            *(v4f*)(Co + (size_t)m * N + nb + tn) = v;
        }
    } else {
        float* base = Cp + (size_t)blockIdx.y * 64 * N;
        #pragma unroll
        for (int i = 0; i < 2; i++) {
            int m = tm + i;
            float* p = base + (size_t)m * N + nb + tn;
            v4f v;
            if (accum) {
                v4f old = *(const v4f*)p;
                #pragma unroll
                for (int j = 0; j < 4; j++) v[j] = old[j] + acc[i][j];
            } else {
                #pragma unroll
                for (int j = 0; j < 4; j++) v[j] = acc[i][j];
            }
            *(v4f*)p = v;
        }
    }
}

// sum Y partial slices Cp[y][len], add bias, optional relu
__global__ void finish2_k(const float* __restrict__ Cp, int Y, int len,
                          const float* __restrict__ bias, int nmask, int relu,
                          float* __restrict__ o) {
    int i = blockIdx.x * 256 + threadIdx.x;
    float s = bias[i & nmask];
    for (int y = 0; y < Y; y++) s += Cp[(size_t)y * len + i];
    if (relu) s = fmaxf(s, 0.f);
    o[i] = s;
}

// fused: reduce nn2 partials inline, concat with hidden, classify + log_softmax
__global__ void sum2f_k(const float* __restrict__ xh, const float* __restrict__ cpn,
                        const float* __restrict__ nn2b,
                        const float* __restrict__ w, const float* __restrict__ bias,
                        float* __restrict__ out) {
    int b = blockIdx.x;
    int lane = threadIdx.x;
    float xc[16];
    #pragma unroll
    for (int j = 0; j < 8; j++) xc[j] = xh[b * FC1F + j * 64 + lane];
    #pragma unroll
    for (int j = 0; j < 8; j++) {
        int n = j * 64 + lane;
        float s = nn2b[n];
        #pragma unroll
        for (int y = 0; y < 4; y++) s += cpn[(size_t)y * (64 * NN2F) + b * NN2F + n];
        xc[8 + j] = fmaxf(s, 0.f);
    }
    float logits[OUTC];
    #pragma unroll
    for (int o = 0; o < OUTC; o++) {
        float s = 0.f;
        #pragma unroll
        for (int j = 0; j < 16; j++) s += xc[j] * w[o * 1024 + j * 64 + lane];
        #pragma unroll
        for (int off = 32; off; off >>= 1) s += __shfl_xor(s, off);
        logits[o] = s + bias[o];
    }
    float mx = logits[0];
    #pragma unroll
    for (int o = 1; o < OUTC; o++) mx = fmaxf(mx, logits[o]);
    float lse = 0.f;
    #pragma unroll
    for (int o = 0; o < OUTC; o++) lse += expf(logits[o] - mx);
    float lg = logf(lse) + mx;
    if (lane < OUTC) out[b * OUTC + lane] = logits[lane] - lg;
}

extern "C" void kernel_launch(void* const* d_in, const int* in_sizes, int n_in,
                              void* d_out, int out_size, void* d_ws, size_t ws_size,
                              hipStream_t stream) {
    const float* x_in   = (const float*)d_in[0];
    const float* L_vals = (const float*)d_in[1];
    const float* cl1_w  = (const float*)d_in[2];
    const float* cl1_b  = (const float*)d_in[3];
    const float* fc1_w  = (const float*)d_in[4];
    const float* fc1_b  = (const float*)d_in[5];
    const float* fc2_w  = (const float*)d_in[6];
    const float* fc2_b  = (const float*)d_in[7];
    const float* fc3_w  = (const float*)d_in[8];
    const float* fc3_b  = (const float*)d_in[9];
    const float* nn1_w  = (const float*)d_in[10];
    const float* nn1_b  = (const float*)d_in[11];
    const float* nn2_w  = (const float*)d_in[12];
    const float* nn2_b  = (const float*)d_in[13];
    const float* sum2_w = (const float*)d_in[14];
    const float* sum2_b = (const float*)d_in[15];
    const int* L_rows = (const int*)d_in[16];
    const int* L_cols = (const int*)d_in[17];
    float* out = (float*)d_out;
    char* ws = (char*)d_ws;

    unsigned short* xs     = (unsigned short*)(ws + OFF_XS);
    unsigned short* scol   = (unsigned short*)(ws + OFF_SCOL);
    unsigned short* sval   = (unsigned short*)(ws + OFF_SVAL);
    int*            rstart = (int*)(ws + OFF_RSTART);
    int*            cnt    = (int*)(ws + OFF_CNT);
    float*          xd     = (float*)(ws + OFF_XD);
    float*          xn1    = (float*)(ws + OFF_XN1);
    unsigned short* sliceq = (unsigned short*)(ws + OFF_SCOL);  // 2 MB quarter-slice (scol+sval dead)
    float*          cp_nn1 = (float*)(ws + OFF_XS);             // 4 MB (xs dead after fc1)
    float*          cp_nn2 = (float*)(ws + OFF_CPN2);           // 512 KB

    float* out_decode = out;                            // f32 [64,16384]; fc1 Cp scratch before fc3
    float* out_hidden = out + (size_t)B_ * V_;          // f32 [64,512]
    float* out_logp   = out_hidden + B_ * FC1F;         // f32 [64,10]
    float* cp_fc1     = out_decode;                     // Cp[32][64][512] = 4 MB exactly

    size_t VB = (size_t)V_ * B_;

    // front: 9 launches
    hipMemsetAsync(cnt, 0, V_ * sizeof(int), stream);
    prepcount_k<<<768, 256, 0, stream>>>(x_in, xs, L_rows, cnt);
    scan_k<<<1, 256, 0, stream>>>(cnt, rstart);
    scatter_k<<<512, 256, 0, stream>>>(L_rows, L_cols, L_vals, cnt, scol, sval);
    spmm_k<<<V_ / 4, 256, 0, stream>>>(rstart, scol, sval, xs, nullptr, xs + VB, 0);
    for (int k = 2; k < KCH; k++)
        spmm_k<<<V_ / 4, 256, 0, stream>>>(rstart, scol, sval,
                                           xs + (k - 1) * VB, xs + (k - 2) * VB, xs + k * VB, 1);

    // fc1: 4 x (quarter cheby + quarter gemm with y=32 K-split) + finish = 9 launches
    for (int q = 0; q < 4; q++) {
        cheby_q_k<<<512, 256, 0, stream>>>(xs, cl1_w, cl1_b, sliceq, q);
        gemm4_k<<<dim3(FC1F / 32, 32), 256, 0, stream>>>(sliceq, 0, 16384, 0,
                                                         fc1_w, FIN1, q * 16384,
                                                         512, FC1F, nullptr, 0, 0, q ? 1 : 0,
                                                         cp_fc1, nullptr);
    }
    finish2_k<<<B_ * FC1F / 256, 256, 0, stream>>>(cp_fc1, 32, B_ * FC1F, fc1_b, FC1F - 1, 1,
                                                   out_hidden);

    // back: 6 launches
    // fc2 direct (16 blocks, K=512) -> xd
    gemm4_k<<<dim3(FC2F / 32, 1), 256, 0, stream>>>(out_hidden, 1, FC1F, 0,
                                                    fc2_w, FC1F, 0,
                                                    FC1F, FC2F, fc2_b, 1, 1, 0, nullptr, xd);
    // fc3 direct (512 blocks, K=512) -> out_decode (consumes cp_fc1 region AFTER finish)
    gemm4_k<<<dim3(V_ / 32, 1), 256, 0, stream>>>(xd, 1, FC2F, 0,
                                                  fc3_w, FC2F, 0,
                                                  FC2F, V_, fc3_b, 0, 1, 0, nullptr, out_decode);
    // nn1 K-split (32 nb x 16 y = 512 blocks, klen=1024) -> cp_nn1, finish -> xn1
    gemm4_k<<<dim3(NN1F / 32, 16), 256, 0, stream>>>(x_in, 1, V_, 0,
                                                     nn1_w, V_, 0,
                                                     1024, NN1F, nullptr, 0, 0, 0, cp_nn1, nullptr);
    finish2_k<<<B_ * NN1F / 256, 256, 0, stream>>>(cp_nn1, 16, B_ * NN1F, nn1_b, NN1F - 1, 1, xn1);
    // nn2 K-split (16 nb x 4 y = 64 blocks, klen=256) -> cp_nn2 ; reduce fused into sum2
    gemm4_k<<<dim3(NN2F / 32, 4), 256, 0, stream>>>(xn1, 1, NN1F, 0,
                                                    nn2_w, NN1F, 0,
                                                    256, NN2F, nullptr, 0, 0, 0, cp_nn2, nullptr);
    sum2f_k<<<B_, 64, 0, stream>>>(out_hidden, cp_nn2, nn2_b, sum2_w, sum2_b, out_logp);
}